// Round 1
// baseline (74.145 us; speedup 1.0000x reference)
//
#include <hip/hip_runtime.h>

#define TH 16
#define TW 16
#define LDW (TW + 3)  // 19-float row stride: odd => decent bank spread

__global__ __launch_bounds__(256) void depth_up_fused(
    const float* __restrict__ depth,
    const float* __restrict__ cv,
    const float* __restrict__ w1,   // [8,8,3,3]
    const float* __restrict__ b1,   // [8]
    const float* __restrict__ w2,   // [36,8]
    const float* __restrict__ b2,   // [36]
    float* __restrict__ out)        // [N, 2H, 2W]
{
    const int N = 4, H = 512, W = 640;
    (void)N;
    const int n  = blockIdx.z;
    const int h0 = blockIdx.y * TH;
    const int w0 = blockIdx.x * TW;
    const int tx = threadIdx.x;
    const int ty = threadIdx.y;
    const int tid = ty * TW + tx;

    __shared__ float s_cv[8][TH + 2][LDW];
    __shared__ float s_d[TH + 2][LDW];

    // ---- stage 8 cv channel tiles + depth tile (with zero halo) into LDS ----
    const int ntile = (TH + 2) * (TW + 2);  // 324
    #pragma unroll
    for (int p = 0; p < 9; ++p) {
        const float* __restrict__ src = (p < 8)
            ? (cv + (size_t)(n * 8 + p) * H * W)
            : (depth + (size_t)n * H * W);
        float* dst = (p < 8) ? &s_cv[p][0][0] : &s_d[0][0];
        for (int i = tid; i < ntile; i += TH * TW) {
            const int r = i / (TW + 2);
            const int c = i - r * (TW + 2);
            const int gh = h0 + r - 1;
            const int gw = w0 + c - 1;
            float v = 0.0f;
            if ((unsigned)gh < (unsigned)H && (unsigned)gw < (unsigned)W)
                v = src[(size_t)gh * W + gw];
            dst[r * LDW + c] = v;
        }
    }
    __syncthreads();

    // ---- conv1: 3x3, 8->8, relu ----
    float acc[8];
    #pragma unroll
    for (int o = 0; o < 8; ++o) acc[o] = b1[o];

    #pragma unroll
    for (int c = 0; c < 8; ++c) {
        float v[9];
        #pragma unroll
        for (int ky = 0; ky < 3; ++ky)
            #pragma unroll
            for (int kx = 0; kx < 3; ++kx)
                v[ky * 3 + kx] = s_cv[c][ty + ky][tx + kx];
        #pragma unroll
        for (int o = 0; o < 8; ++o) {
            const float* wp = w1 + (o * 8 + c) * 9;  // uniform -> s_load
            #pragma unroll
            for (int t = 0; t < 9; ++t)
                acc[o] += v[t] * wp[t];
        }
    }
    #pragma unroll
    for (int o = 0; o < 8; ++o) acc[o] = fmaxf(acc[o], 0.0f);

    // ---- conv2: 1x1, 8->36, * 0.25 ----
    float mask[36];
    #pragma unroll
    for (int m = 0; m < 36; ++m) {
        float s = b2[m];
        const float* wp = w2 + m * 8;  // uniform -> s_load
        #pragma unroll
        for (int c = 0; c < 8; ++c) s += acc[c] * wp[c];
        mask[m] = 0.25f * s;
    }

    // ---- depth 3x3 patch (zero-padded) ----
    float patch[9];
    #pragma unroll
    for (int ky = 0; ky < 3; ++ky)
        #pragma unroll
        for (int kx = 0; kx < 3; ++kx)
            patch[ky * 3 + kx] = s_d[ty + ky][tx + kx];

    // ---- 4 softmaxes over the 9 taps + weighted sum ----
    float res[4];
    #pragma unroll
    for (int q = 0; q < 4; ++q) {
        float mx = mask[q];
        #pragma unroll
        for (int k = 1; k < 9; ++k) mx = fmaxf(mx, mask[k * 4 + q]);
        float sum = 0.0f, r = 0.0f;
        #pragma unroll
        for (int k = 0; k < 9; ++k) {
            const float e = __expf(mask[k * 4 + q] - mx);
            sum += e;
            r += e * patch[k];
        }
        res[q] = r / sum;
    }

    // ---- store 2x2 output pixels (two coalesced float2 stores) ----
    const int h = h0 + ty;
    const int w = w0 + tx;
    const size_t W2 = (size_t)(2 * W);
    float* o0 = out + ((size_t)n * (2 * H) + (size_t)(2 * h)) * W2 + (size_t)(2 * w);
    float* o1 = o0 + W2;
    *reinterpret_cast<float2*>(o0) = make_float2(res[0], res[1]);
    *reinterpret_cast<float2*>(o1) = make_float2(res[2], res[3]);
}

extern "C" void kernel_launch(void* const* d_in, const int* in_sizes, int n_in,
                              void* d_out, int out_size, void* d_ws, size_t ws_size,
                              hipStream_t stream) {
    (void)in_sizes; (void)n_in; (void)out_size; (void)d_ws; (void)ws_size;
    const float* depth = (const float*)d_in[0];
    const float* cv    = (const float*)d_in[1];
    const float* w1    = (const float*)d_in[2];
    const float* b1    = (const float*)d_in[3];
    const float* w2    = (const float*)d_in[4];
    const float* b2    = (const float*)d_in[5];
    float* out = (float*)d_out;

    dim3 grid(640 / TW, 512 / TH, 4);
    dim3 block(TW, TH);
    hipLaunchKernelGGL(depth_up_fused, grid, block, 0, stream,
                       depth, cv, w1, b1, w2, b2, out);
}